// Round 1
// baseline (217.301 us; speedup 1.0000x reference)
//
#include <hip/hip_runtime.h>
#include <math.h>

#define TAIL_B 20.0f
#define KBINS 16
#define GI 512              // G * I = 8 * 64
#define BATCH 16384
#define NELEM (BATCH * GI)  // 8,388,608 elements per output tensor

// Workspace layout (float offsets):
//   cumw : [GI][17] @ 0
//   cumh : [GI][17] @ 8704
//   dknt : [GI][17] @ 17408   (boundary derivatives, [1, softplus(D), 1])
//   invw : [GI][16] @ 26112   (1 / width)
//   hgt  : [GI][16] @ 34304   (height)
//   dlt  : [GI][16] @ 42496   (height / width)
// total 50688 floats = 202,752 bytes
#define OFF_CUMW 0
#define OFF_CUMH 8704
#define OFF_DKNT 17408
#define OFF_INVW 26112
#define OFF_HGT  34304
#define OFF_DLT  42496

__global__ __launch_bounds__(512) void rqs_precompute(
    const float* __restrict__ W, const float* __restrict__ H,
    const float* __restrict__ D, float* __restrict__ ws)
{
    int gi = blockIdx.x * blockDim.x + threadIdx.x;
    if (gi >= GI) return;

    float wl[KBINS], hl[KBINS];
#pragma unroll
    for (int k = 0; k < KBINS; ++k) wl[k] = W[gi * KBINS + k];
#pragma unroll
    for (int k = 0; k < KBINS; ++k) hl[k] = H[gi * KBINS + k];

    float mw = wl[0], mh = hl[0];
#pragma unroll
    for (int k = 1; k < KBINS; ++k) { mw = fmaxf(mw, wl[k]); mh = fmaxf(mh, hl[k]); }
    float sw = 0.0f, sh = 0.0f;
#pragma unroll
    for (int k = 0; k < KBINS; ++k) {
        wl[k] = expf(wl[k] - mw); sw += wl[k];
        hl[k] = expf(hl[k] - mh); sh += hl[k];
    }
    float scw = (2.0f * TAIL_B) / sw;
    float sch = (2.0f * TAIL_B) / sh;

    float* cumw = ws + OFF_CUMW + gi * 17;
    float* cumh = ws + OFF_CUMH + gi * 17;
    float* dknt = ws + OFF_DKNT + gi * 17;
    float* invw = ws + OFF_INVW + gi * 16;
    float* hgt  = ws + OFF_HGT  + gi * 16;
    float* dlt  = ws + OFF_DLT  + gi * 16;

    float cw = -TAIL_B, ch = -TAIL_B;
    cumw[0] = cw; cumh[0] = ch;
#pragma unroll
    for (int k = 0; k < KBINS; ++k) {
        float wk = wl[k] * scw;
        float hk = hl[k] * sch;
        cw += wk; ch += hk;
        cumw[k + 1] = cw;
        cumh[k + 1] = ch;
        invw[k] = 1.0f / wk;
        hgt[k]  = hk;
        dlt[k]  = hk / wk;
    }
    dknt[0] = 1.0f;
    dknt[16] = 1.0f;
#pragma unroll
    for (int k = 0; k < KBINS - 1; ++k) {
        float v = D[gi * (KBINS - 1) + k];
        // stable softplus: max(v,0) + log1p(exp(-|v|))
        dknt[k + 1] = fmaxf(v, 0.0f) + log1pf(expf(-fabsf(v)));
    }
}

__global__ __launch_bounds__(256) void rqs_main(
    const float* __restrict__ x, const float* __restrict__ ws,
    float* __restrict__ out)
{
    int t = blockIdx.x * 256 + threadIdx.x;
    int e4 = t * 4;
    if (e4 >= NELEM) return;

    float4 xv = *reinterpret_cast<const float4*>(x + e4);
    float xs[4] = {xv.x, xv.y, xv.z, xv.w};
    float zs[4], ls[4];

#pragma unroll
    for (int j = 0; j < 4; ++j) {
        int gi = (e4 + j) & (GI - 1);
        float xx = xs[j];
        bool inside = (xx >= -TAIL_B) && (xx <= TAIL_B);
        float xc = fminf(fmaxf(xx, -TAIL_B), TAIL_B);

        const float* cumw = ws + OFF_CUMW + gi * 17;
        // binary search: largest idx in [0,15] with cumw[idx] <= xc
        int idx = 0;
#pragma unroll
        for (int s = 8; s >= 1; s >>= 1) {
            int tst = idx + s;
            if (xc >= cumw[tst]) idx = tst;
        }

        float cw0 = cumw[idx];
        float ch0 = ws[OFF_CUMH + gi * 17 + idx];
        float d0  = ws[OFF_DKNT + gi * 17 + idx];
        float d1  = ws[OFF_DKNT + gi * 17 + idx + 1];
        float iw  = ws[OFF_INVW + gi * 16 + idx];
        float hh  = ws[OFF_HGT  + gi * 16 + idx];
        float de  = ws[OFF_DLT  + gi * 16 + idx];

        float theta = (xc - cw0) * iw;
        float omt   = 1.0f - theta;
        float tt    = theta * omt;
        float denom = de + (d0 + d1 - 2.0f * de) * tt;
        float numer = hh * (de * theta * theta + d0 * tt);
        float zin   = ch0 + numer / denom;
        float dnum  = de * de * (d1 * theta * theta + 2.0f * de * tt + d0 * omt * omt);
        // ld = ln(dnum) - 2*ln(denom) = ln2 * (log2(dnum) - 2*log2(denom))
        float ldin  = 0.6931471805599453f * (__log2f(dnum) - 2.0f * __log2f(denom));

        zs[j] = inside ? zin : xx;
        ls[j] = inside ? ldin : 0.0f;
    }

    *reinterpret_cast<float4*>(out + e4)         = make_float4(zs[0], zs[1], zs[2], zs[3]);
    *reinterpret_cast<float4*>(out + NELEM + e4) = make_float4(ls[0], ls[1], ls[2], ls[3]);
}

extern "C" void kernel_launch(void* const* d_in, const int* in_sizes, int n_in,
                              void* d_out, int out_size, void* d_ws, size_t ws_size,
                              hipStream_t stream)
{
    const float* x = (const float*)d_in[0];
    const float* W = (const float*)d_in[1];
    const float* H = (const float*)d_in[2];
    const float* D = (const float*)d_in[3];
    float* out = (float*)d_out;
    float* ws  = (float*)d_ws;

    rqs_precompute<<<1, 512, 0, stream>>>(W, H, D, ws);

    int nthreads = NELEM / 4;              // 2,097,152
    int nblocks  = nthreads / 256;         // 8192
    rqs_main<<<nblocks, 256, 0, stream>>>(x, ws, out);
}

// Round 2
// 45.713 us; speedup vs baseline: 4.7536x; 4.7536x over previous
//
#include <hip/hip_runtime.h>
#include <math.h>

#define TAIL_B 20.0f
#define KBINS 16
#define GI 512              // G * I = 8 * 64
#define BATCH 16384
#define NELEM (BATCH * GI)  // 8,388,608 elements per output tensor
#define BB 64               // batch rows per block

// Workspace layout (float offsets):
//   cumw : [GI][17]          @ 0        (8704 floats)
//   rec0 : [GI][16] float4   @ 8704     (32768 floats)  (cw0, ch0, d0, d1)
//   rec1 : [GI][16] float4   @ 41472    (32768 floats)  (1/w, h, delta, 0)
// total 74240 floats = 296,960 bytes
#define OFF_CUMW 0
#define OFF_REC0 8704
#define OFF_REC1 41472

__global__ __launch_bounds__(512) void rqs_precompute(
    const float* __restrict__ W, const float* __restrict__ H,
    const float* __restrict__ D, float* __restrict__ ws)
{
    int gi = threadIdx.x;
    if (gi >= GI) return;

    float wl[KBINS], hl[KBINS], dk[KBINS + 1];
#pragma unroll
    for (int k = 0; k < KBINS; ++k) wl[k] = W[gi * KBINS + k];
#pragma unroll
    for (int k = 0; k < KBINS; ++k) hl[k] = H[gi * KBINS + k];

    float mw = wl[0], mh = hl[0];
#pragma unroll
    for (int k = 1; k < KBINS; ++k) { mw = fmaxf(mw, wl[k]); mh = fmaxf(mh, hl[k]); }
    float sw = 0.0f, sh = 0.0f;
#pragma unroll
    for (int k = 0; k < KBINS; ++k) {
        wl[k] = expf(wl[k] - mw); sw += wl[k];
        hl[k] = expf(hl[k] - mh); sh += hl[k];
    }
    float scw = (2.0f * TAIL_B) / sw;
    float sch = (2.0f * TAIL_B) / sh;

    dk[0] = 1.0f;
    dk[KBINS] = 1.0f;
#pragma unroll
    for (int k = 0; k < KBINS - 1; ++k) {
        float v = D[gi * (KBINS - 1) + k];
        dk[k + 1] = fmaxf(v, 0.0f) + log1pf(expf(-fabsf(v)));  // stable softplus
    }

    float*  cumw = ws + OFF_CUMW + gi * 17;
    float4* rec0 = reinterpret_cast<float4*>(ws + OFF_REC0) + gi * 16;
    float4* rec1 = reinterpret_cast<float4*>(ws + OFF_REC1) + gi * 16;

    float cw = -TAIL_B, ch = -TAIL_B;
    cumw[0] = cw;
#pragma unroll
    for (int k = 0; k < KBINS; ++k) {
        float wk = wl[k] * scw;
        float hk = hl[k] * sch;
        float cw_k = cw, ch_k = ch;
        cw += wk; ch += hk;
        cumw[k + 1] = cw;
        rec0[k] = make_float4(cw_k, ch_k, dk[k], dk[k + 1]);
        rec1[k] = make_float4(1.0f / wk, hk, hk / wk, 0.0f);
    }
}

__global__ __launch_bounds__(256, 4) void rqs_main(
    const float* __restrict__ x, const float* __restrict__ ws,
    float* __restrict__ out)
{
    __shared__ float  s_cumw[64 * 17];   //  4352 B
    __shared__ float4 s_r0[64 * 16];     // 16384 B
    __shared__ float4 s_r1[64 * 16];     // 16384 B  -> 37,120 B total

    int g     = blockIdx.x & 7;
    int chunk = blockIdx.x >> 3;

    // ---- stage this g's tables into LDS (coalesced) ----
    const float*  gcumw = ws + OFF_CUMW + g * 64 * 17;
    const float4* gr0   = reinterpret_cast<const float4*>(ws + OFF_REC0) + g * 64 * 16;
    const float4* gr1   = reinterpret_cast<const float4*>(ws + OFF_REC1) + g * 64 * 16;

    for (int it = threadIdx.x; it < 64 * 17; it += 256) s_cumw[it] = gcumw[it];
    for (int it = threadIdx.x; it < 64 * 16; it += 256) {
        int i = it >> 4, k = it & 15;
        int ks = k ^ (i & 7);            // bank-group swizzle
        s_r0[i * 16 + ks] = gr0[it];
        s_r1[i * 16 + ks] = gr1[it];
    }
    __syncthreads();

    // ---- process 64 rows x 64 cols tile, 16 elems/thread as 4x float4 ----
    int base = chunk * (BB * 512) + g * 64;   // x index of tile row 0, col 0

#pragma unroll
    for (int r = 0; r < 4; ++r) {
        int te   = r * 1024 + threadIdx.x * 4;  // tile-element index, %4==0
        int brow = te >> 6;
        int icol = te & 63;                      // in {0,4,...,60}
        int addr = base + brow * 512 + icol;

        float4 xv = *reinterpret_cast<const float4*>(x + addr);
        float xs[4] = {xv.x, xv.y, xv.z, xv.w};
        float zs[4], ls[4];

#pragma unroll
        for (int j = 0; j < 4; ++j) {
            int   il = icol + j;                 // local gi (0..63)
            float xx = xs[j];
            bool  inside = (xx >= -TAIL_B) && (xx <= TAIL_B);
            float xc = fminf(fmaxf(xx, -TAIL_B), TAIL_B);

            const float* cw = s_cumw + il * 17;
            int idx = 0;
#pragma unroll
            for (int s = 8; s >= 1; s >>= 1) {
                if (xc >= cw[idx + s]) idx += s;
            }

            int    ks = idx ^ (il & 7);
            float4 r0 = s_r0[il * 16 + ks];      // cw0, ch0, d0, d1
            float4 r1 = s_r1[il * 16 + ks];      // 1/w, h, delta

            float theta = (xc - r0.x) * r1.x;
            float omt   = 1.0f - theta;
            float tt    = theta * omt;
            float de    = r1.z;
            float denom = de + (r0.z + r0.w - 2.0f * de) * tt;
            float numer = r1.y * (de * theta * theta + r0.z * tt);
            float rden  = __builtin_amdgcn_rcpf(denom);
            float zin   = r0.y + numer * rden;
            float dnum  = de * de * (r0.w * theta * theta + 2.0f * de * tt + r0.z * omt * omt);
            float ldin  = 0.6931471805599453f * (__log2f(dnum) - 2.0f * __log2f(denom));

            zs[j] = inside ? zin : xx;
            ls[j] = inside ? ldin : 0.0f;
        }

        *reinterpret_cast<float4*>(out + addr)         = make_float4(zs[0], zs[1], zs[2], zs[3]);
        *reinterpret_cast<float4*>(out + NELEM + addr) = make_float4(ls[0], ls[1], ls[2], ls[3]);
    }
}

extern "C" void kernel_launch(void* const* d_in, const int* in_sizes, int n_in,
                              void* d_out, int out_size, void* d_ws, size_t ws_size,
                              hipStream_t stream)
{
    const float* x = (const float*)d_in[0];
    const float* W = (const float*)d_in[1];
    const float* H = (const float*)d_in[2];
    const float* D = (const float*)d_in[3];
    float* out = (float*)d_out;
    float* ws  = (float*)d_ws;

    rqs_precompute<<<1, 512, 0, stream>>>(W, H, D, ws);

    int nblocks = 8 * (BATCH / BB);   // 8 g * 256 chunks = 2048 blocks
    rqs_main<<<nblocks, 256, 0, stream>>>(x, ws, out);
}

// Round 3
// 44.926 us; speedup vs baseline: 4.8368x; 1.0175x over previous
//
#include <hip/hip_runtime.h>
#include <math.h>

#define TAIL_B 20.0f
#define KBINS 16
#define GI 512              // G * I = 8 * 64
#define BATCH 16384
#define NELEM (BATCH * GI)  // 8,388,608 elements per output tensor

// One fused kernel. Each block owns one g (64 gi columns) x 64 batch rows.
// Threads 0-63 rebuild the spline tables for this g directly into LDS
// (redundant across blocks, but fully parallel and ~free vs. a serial
// 1-block precompute launch). LDS = 24.5 KB -> 6 blocks/CU.
__global__ __launch_bounds__(256, 6) void rqs_fused(
    const float* __restrict__ x, const float* __restrict__ W,
    const float* __restrict__ H, const float* __restrict__ D,
    float* __restrict__ out)
{
    __shared__ float  s_cumw[64 * 17];   // left knots, entries 0..15, stride-17 pad
    __shared__ float  s_h[64 * 17];      // bin heights, stride-17 pad
    __shared__ float4 s_rec[64 * 16];    // (ch0, d0, d1, invw), xor-swizzled

    int g     = blockIdx.x & 7;
    int chunk = blockIdx.x >> 3;
    int tid   = threadIdx.x;

    // ---- per-block table build (threads 0..63, one per il) ----
    if (tid < 64) {
        int il = tid;
        int gi = g * 64 + il;
        const float* Wg = W + gi * 16;
        const float* Hg = H + gi * 16;
        const float* Dg = D + gi * 15;

        float mw = Wg[0], mh = Hg[0];
#pragma unroll
        for (int k = 1; k < 16; ++k) { mw = fmaxf(mw, Wg[k]); mh = fmaxf(mh, Hg[k]); }
        float sw = 0.0f, sh = 0.0f;
#pragma unroll
        for (int k = 0; k < 16; ++k) { sw += expf(Wg[k] - mw); sh += expf(Hg[k] - mh); }
        float scw = (2.0f * TAIL_B) / sw;
        float sch = (2.0f * TAIL_B) / sh;

        float cw = -TAIL_B, ch = -TAIL_B, dprev = 1.0f;
#pragma unroll
        for (int k = 0; k < 16; ++k) {
            float wk = expf(Wg[k] - mw) * scw;
            float hk = expf(Hg[k] - mh) * sch;
            float dnext = 1.0f;
            if (k < 15) {
                float v = Dg[k];
                dnext = fmaxf(v, 0.0f) + log1pf(expf(-fabsf(v)));  // stable softplus
            }
            s_cumw[il * 17 + k] = cw;
            s_h[il * 17 + k]    = hk;
            s_rec[il * 16 + (k ^ (il & 7))] = make_float4(ch, dprev, dnext, 1.0f / wk);
            cw += wk; ch += hk; dprev = dnext;
        }
    }
    __syncthreads();

    // ---- 64 rows x 64 cols tile; 16 elems/thread; all x loads prefetched ----
    int base = chunk * (64 * 512) + g * 64;
    int icol = (tid * 4) & 63;        // this thread's 4 columns (constant over r)
    int row0 = tid >> 4;

    float4 xv[4];
#pragma unroll
    for (int r = 0; r < 4; ++r)
        xv[r] = *reinterpret_cast<const float4*>(x + base + (r * 16 + row0) * 512 + icol);

#pragma unroll
    for (int r = 0; r < 4; ++r) {
        int addr = base + (r * 16 + row0) * 512 + icol;
        float xs[4] = {xv[r].x, xv[r].y, xv[r].z, xv[r].w};
        float zs[4], ls[4];

#pragma unroll
        for (int j = 0; j < 4; ++j) {
            int   il = icol + j;
            float xx = xs[j];
            bool  inside = (xx >= -TAIL_B) && (xx <= TAIL_B);
            float xc = fminf(fmaxf(xx, -TAIL_B), TAIL_B);

            // binary search; tracks the accepted knot value -> cw0 for free
            const float* cwp = s_cumw + il * 17;
            int   idx = 0;
            float cw0 = -TAIL_B;
#pragma unroll
            for (int s = 8; s >= 1; s >>= 1) {
                float v = cwp[idx + s];            // max index 15
                if (xc >= v) { idx += s; cw0 = v; }
            }

            float4 rc = s_rec[il * 16 + (idx ^ (il & 7))];  // ch0, d0, d1, invw
            float  hh = s_h[il * 17 + idx];

            float invw  = rc.w;
            float theta = (xc - cw0) * invw;
            float omt   = 1.0f - theta;
            float tt    = theta * omt;
            float de    = hh * invw;
            float denom = de + (rc.y + rc.z - 2.0f * de) * tt;
            float numer = hh * (de * theta * theta + rc.y * tt);
            float rden  = __builtin_amdgcn_rcpf(denom);
            float zin   = rc.x + numer * rden;
            float dnum  = de * de * (rc.z * theta * theta + 2.0f * de * tt + rc.y * omt * omt);
            float ldin  = 0.6931471805599453f * (__log2f(dnum) - 2.0f * __log2f(denom));

            zs[j] = inside ? zin : xx;
            ls[j] = inside ? ldin : 0.0f;
        }

        *reinterpret_cast<float4*>(out + addr)         = make_float4(zs[0], zs[1], zs[2], zs[3]);
        *reinterpret_cast<float4*>(out + NELEM + addr) = make_float4(ls[0], ls[1], ls[2], ls[3]);
    }
}

extern "C" void kernel_launch(void* const* d_in, const int* in_sizes, int n_in,
                              void* d_out, int out_size, void* d_ws, size_t ws_size,
                              hipStream_t stream)
{
    const float* x = (const float*)d_in[0];
    const float* W = (const float*)d_in[1];
    const float* H = (const float*)d_in[2];
    const float* D = (const float*)d_in[3];
    float* out = (float*)d_out;

    rqs_fused<<<8 * (BATCH / 64), 256, 0, stream>>>(x, W, H, D, out);
}

// Round 4
// 34.912 us; speedup vs baseline: 6.2242x; 1.2868x over previous
//
#include <hip/hip_runtime.h>
#include <math.h>

#define TAIL_B 20.0f
#define KBINS 16
#define GI 512              // G * I = 8 * 64
#define BATCH 16384
#define NELEM (BATCH * GI)  // 8,388,608 elements per output tensor
#define ROWS_PB 32          // batch rows per main-kernel block

// Per-g workspace image (float offsets within a 6144-float region), laid out
// exactly as the main kernel's LDS, with the xor-swizzle PRE-APPLIED:
//   cumw : [64][16] @ 0      left knots k=1..15 at slot (k ^ ((il>>2)&15))
//   h    : [64][16] @ 1024   bin heights at slot (k ^ ((il>>2)&15))
//   rec  : [64][16] float4 @ 2048  (ch0, d0, d1, invw) at slot (k ^ ((il>>2)&7))
// total ws = 8 * 6144 floats = 196,608 bytes

__global__ __launch_bounds__(256) void rqs_precompute(
    const float* __restrict__ W, const float* __restrict__ H,
    const float* __restrict__ D, float* __restrict__ ws)
{
    int gi = blockIdx.x * 256 + threadIdx.x;
    if (gi >= GI) return;
    int g  = gi >> 6, il = gi & 63;
    int sw  = (il >> 2) & 15;
    int sw8 = (il >> 2) & 7;

    float*  base = ws + g * 6144;
    float*  cumw = base;
    float*  harr = base + 1024;
    float4* rec  = reinterpret_cast<float4*>(base + 2048);

    const float* Wg = W + gi * 16;
    const float* Hg = H + gi * 16;
    const float* Dg = D + gi * 15;

    float mw = Wg[0], mh = Hg[0];
#pragma unroll
    for (int k = 1; k < 16; ++k) { mw = fmaxf(mw, Wg[k]); mh = fmaxf(mh, Hg[k]); }
    float sumw = 0.0f, sumh = 0.0f;
#pragma unroll
    for (int k = 0; k < 16; ++k) { sumw += expf(Wg[k] - mw); sumh += expf(Hg[k] - mh); }
    float scw = (2.0f * TAIL_B) / sumw;
    float sch = (2.0f * TAIL_B) / sumh;

    cumw[il * 16 + sw] = -TAIL_B;   // unused slot (logical k=0), init anyway

    float cw = -TAIL_B, ch = -TAIL_B, dprev = 1.0f;
#pragma unroll
    for (int k = 0; k < 16; ++k) {
        float wk = expf(Wg[k] - mw) * scw;
        float hk = expf(Hg[k] - mh) * sch;
        float dnext = 1.0f;
        if (k < 15) {
            float v = Dg[k];
            dnext = fmaxf(v, 0.0f) + log1pf(expf(-fabsf(v)));  // stable softplus
        }
        if (k >= 1) cumw[il * 16 + (k ^ sw)] = cw;   // left knot of bin k
        harr[il * 16 + (k ^ sw)]  = hk;
        rec[il * 16 + (k ^ sw8)]  = make_float4(ch, dprev, dnext, 1.0f / wk);
        cw += wk; ch += hk; dprev = dnext;
    }
}

__global__ __launch_bounds__(256, 6) void rqs_main(
    const float* __restrict__ x, const float* __restrict__ ws,
    float* __restrict__ out)
{
    __shared__ float s_tab[6144];   // 24,576 B -> 6 blocks/CU

    int g     = blockIdx.x & 7;
    int chunk = blockIdx.x >> 3;
    int tid   = threadIdx.x;

    // ---- stage pre-swizzled table image (coalesced, no math) ----
    {
        float4*       dst = reinterpret_cast<float4*>(s_tab);
        const float4* src = reinterpret_cast<const float4*>(ws + g * 6144);
#pragma unroll
        for (int i = 0; i < 6; ++i) dst[tid + 256 * i] = src[tid + 256 * i];
    }
    __syncthreads();

    const float*  s_cumw = s_tab;
    const float*  s_h    = s_tab + 1024;
    const float4* s_rec  = reinterpret_cast<const float4*>(s_tab + 2048);

    // ---- 32 rows x 64 cols tile; 8 elems/thread as 2 float4 ----
    int base = chunk * (ROWS_PB * 512) + g * 64;
    int icol = (tid * 4) & 63;       // 4 columns, constant across r
    int row0 = tid >> 4;             // 0..15

    float4 xv[2];
    xv[0] = *reinterpret_cast<const float4*>(x + base + row0 * 512 + icol);
    xv[1] = *reinterpret_cast<const float4*>(x + base + (row0 + 16) * 512 + icol);

#pragma unroll
    for (int r = 0; r < 2; ++r) {
        int addr = base + (row0 + r * 16) * 512 + icol;
        float xs[4] = {xv[r].x, xv[r].y, xv[r].z, xv[r].w};
        float zs[4], ls[4];

#pragma unroll
        for (int j = 0; j < 4; ++j) {
            int   il  = icol + j;
            int   sw  = (il >> 2) & 15;
            int   sw8 = (il >> 2) & 7;
            float xx  = xs[j];
            bool  inside = (xx >= -TAIL_B) && (xx <= TAIL_B);
            float xc  = fminf(fmaxf(xx, -TAIL_B), TAIL_B);

            const float* cwp = s_cumw + il * 16;
            int   idx = 0;
            float cw0 = -TAIL_B;
#pragma unroll
            for (int s = 8; s >= 1; s >>= 1) {
                float v = cwp[(idx + s) ^ sw];     // logical knot idx+s (1..15)
                if (xc >= v) { idx += s; cw0 = v; }
            }

            float4 rc = s_rec[il * 16 + (idx ^ sw8)];  // ch0, d0, d1, invw
            float  hh = s_h[il * 16 + (idx ^ sw)];

            float invw  = rc.w;
            float theta = (xc - cw0) * invw;
            float omt   = 1.0f - theta;
            float tt    = theta * omt;
            float de    = hh * invw;
            float denom = de + (rc.y + rc.z - 2.0f * de) * tt;
            float rden  = __builtin_amdgcn_rcpf(denom);
            float numer = hh * (de * theta * theta + rc.y * tt);
            float zin   = rc.x + numer * rden;
            float dnum  = de * de * (rc.z * theta * theta + 2.0f * de * tt + rc.y * omt * omt);
            // ld = ln(dnum) - 2 ln(denom) = ln(dnum * rden^2): ONE log
            float ldin  = 0.6931471805599453f * __log2f(dnum * rden * rden);

            zs[j] = inside ? zin : xx;
            ls[j] = inside ? ldin : 0.0f;
        }

        *reinterpret_cast<float4*>(out + addr)         = make_float4(zs[0], zs[1], zs[2], zs[3]);
        *reinterpret_cast<float4*>(out + NELEM + addr) = make_float4(ls[0], ls[1], ls[2], ls[3]);
    }
}

extern "C" void kernel_launch(void* const* d_in, const int* in_sizes, int n_in,
                              void* d_out, int out_size, void* d_ws, size_t ws_size,
                              hipStream_t stream)
{
    const float* x = (const float*)d_in[0];
    const float* W = (const float*)d_in[1];
    const float* H = (const float*)d_in[2];
    const float* D = (const float*)d_in[3];
    float* out = (float*)d_out;
    float* ws  = (float*)d_ws;

    rqs_precompute<<<GI / 256, 256, 0, stream>>>(W, H, D, ws);

    int nblocks = 8 * (BATCH / ROWS_PB);   // 8 g * 512 chunks = 4096 blocks
    rqs_main<<<nblocks, 256, 0, stream>>>(x, ws, out);
}

// Round 5
// 34.835 us; speedup vs baseline: 6.2380x; 1.0022x over previous
//
#include <hip/hip_runtime.h>
#include <math.h>

#define TAIL_B 20.0f
#define GI 512              // G * I = 8 * 64
#define BATCH 16384
#define NELEM (BATCH * GI)  // 8,388,608 elements per output tensor
#define ROWS_PB 32          // batch rows per main-kernel block

typedef float vf4 __attribute__((ext_vector_type(4)));
typedef float vf2 __attribute__((ext_vector_type(2)));

// Per-g workspace image (float offsets within GSTRIDE region):
//   coarse_T [3][64]        @ 0     knot4/knot8/knot12, transposed (reg-loaded)
//   knots_T  [12][64]       @ 192   row 3c+j' = knot_{4c+1+j'}, transposed
//   rec0     [64][16] vf4   @ 960   (cw0, ch0, d0, d1) at slot k ^ (m&7)
//   rec1     [64][16] vf2   @ 5056  (invw, h)          at slot k ^ m
// (m = il>>2).  Total per g: 7104 floats; ws = 8*7104*4 = 227,328 B.
#define GSTRIDE 7104
#define OFF_COARSE 0
#define OFF_KNT 192
#define OFF_REC0 960
#define OFF_REC1 5056
// LDS image (excludes coarse): knots_T @0 (768), rec0 @768 (4096), rec1 @4864 (2048)
#define LDS_FLOATS 6912

__global__ __launch_bounds__(256) void rqs_precompute(
    const float* __restrict__ W, const float* __restrict__ H,
    const float* __restrict__ D, float* __restrict__ ws)
{
    int gi = blockIdx.x * 256 + threadIdx.x;
    if (gi >= GI) return;
    int g = gi >> 6, il = gi & 63;
    int m = il >> 2;                 // 0..15

    float* base = ws + g * GSTRIDE;
    vf4*   rec0 = reinterpret_cast<vf4*>(base + OFF_REC0);
    vf2*   rec1 = reinterpret_cast<vf2*>(base + OFF_REC1);

    const float* Wg = W + gi * 16;
    const float* Hg = H + gi * 16;
    const float* Dg = D + gi * 15;

    float mw = Wg[0], mh = Hg[0];
#pragma unroll
    for (int k = 1; k < 16; ++k) { mw = fmaxf(mw, Wg[k]); mh = fmaxf(mh, Hg[k]); }
    float sumw = 0.0f, sumh = 0.0f;
#pragma unroll
    for (int k = 0; k < 16; ++k) { sumw += expf(Wg[k] - mw); sumh += expf(Hg[k] - mh); }
    float scw = (2.0f * TAIL_B) / sumw;
    float sch = (2.0f * TAIL_B) / sumh;

    float cw = -TAIL_B, ch = -TAIL_B, dprev = 1.0f;
#pragma unroll
    for (int k = 0; k < 16; ++k) {
        float wk = expf(Wg[k] - mw) * scw;
        float hk = expf(Hg[k] - mh) * sch;
        float dnext = 1.0f;
        if (k < 15) {
            float v = Dg[k];
            dnext = fmaxf(v, 0.0f) + log1pf(expf(-fabsf(v)));  // stable softplus
        }
        rec0[il * 16 + (k ^ (m & 7))] = (vf4){cw, ch, dprev, dnext};
        rec1[il * 16 + (k ^ m)]       = (vf2){1.0f / wk, hk};
        cw += wk; ch += hk; dprev = dnext;
        int t = k + 1;                   // knot index of the right edge
        if (t < 16) {
            if ((t & 3) == 0) base[OFF_COARSE + (t / 4 - 1) * 64 + il] = cw;
            else {
                int c = t >> 2, jp = (t & 3) - 1;
                base[OFF_KNT + (3 * c + jp) * 64 + il] = cw;
            }
        }
    }
}

__global__ __launch_bounds__(256, 5) void rqs_main(
    const float* __restrict__ x, const float* __restrict__ ws,
    float* __restrict__ out)
{
    __shared__ float s_tab[LDS_FLOATS];   // 27,648 B -> 5 blocks/CU

    int g     = blockIdx.x & 7;
    int chunk = blockIdx.x >> 3;
    int tid   = threadIdx.x;

    // ---- stage pre-swizzled table image (coalesced, no math) ----
    {
        const vf4* src = reinterpret_cast<const vf4*>(ws + g * GSTRIDE + OFF_KNT);
        vf4*       dst = reinterpret_cast<vf4*>(s_tab);
#pragma unroll
        for (int i = 0; i < 7; ++i) {
            int t4 = tid + 256 * i;
            if (t4 < LDS_FLOATS / 4) dst[t4] = src[t4];
        }
    }

    int icol = (tid * 4) & 63;       // 4 columns, constant across r
    int row0 = tid >> 4;             // 0..15
    int base = chunk * (ROWS_PB * 512) + g * 64;

    // coarse knots (knot4/8/12 per column) -> registers; x -> registers
    const float* cb = ws + g * GSTRIDE + OFF_COARSE;
    vf4 ck4  = *reinterpret_cast<const vf4*>(cb + icol);
    vf4 ck8  = *reinterpret_cast<const vf4*>(cb + 64 + icol);
    vf4 ck12 = *reinterpret_cast<const vf4*>(cb + 128 + icol);
    vf4 xv0  = *reinterpret_cast<const vf4*>(x + base + row0 * 512 + icol);
    vf4 xv1  = *reinterpret_cast<const vf4*>(x + base + (row0 + 16) * 512 + icol);

    __syncthreads();

    const vf4* s_rec0 = reinterpret_cast<const vf4*>(s_tab + 768);
    const vf2* s_rec1 = reinterpret_cast<const vf2*>(s_tab + 4864);

#pragma unroll
    for (int r = 0; r < 2; ++r) {
        float zs[4], ls[4];
#pragma unroll
        for (int j = 0; j < 4; ++j) {
            int   il = icol + j;
            int   m  = il >> 2;
            float xx = r ? xv1[j] : xv0[j];
            bool  inside = (xx >= -TAIL_B) && (xx <= TAIL_B);
            float xc = fminf(fmaxf(xx, -TAIL_B), TAIL_B);

            // coarse: registers only
            int c = (int)(xc >= ck4[j]) + (int)(xc >= ck8[j]) + (int)(xc >= ck12[j]);
            // fine: 3 parallel transposed LDS reads (knots 4c+1..4c+3)
            const float* kt = s_tab + 3 * c * 64 + il;
            float f0 = kt[0], f1 = kt[64], f2 = kt[128];
            int idx = 4 * c + (int)(xc >= f0) + (int)(xc >= f1) + (int)(xc >= f2);

            vf4 r0 = s_rec0[il * 16 + (idx ^ (m & 7))];   // cw0, ch0, d0, d1
            vf2 r1 = s_rec1[il * 16 + (idx ^ m)];         // invw, h

            float invw  = r1.x;
            float hh    = r1.y;
            float de    = hh * invw;
            float theta = (xc - r0.x) * invw;
            float omt   = 1.0f - theta;
            float tt    = theta * omt;
            float denom = de + (r0.z + r0.w - 2.0f * de) * tt;
            float rden  = __builtin_amdgcn_rcpf(denom);
            float numer = hh * (de * theta * theta + r0.z * tt);
            float zin   = r0.y + numer * rden;
            float dnum  = de * de * (r0.w * theta * theta + 2.0f * de * tt + r0.z * omt * omt);
            float ldin  = 0.6931471805599453f * __log2f(dnum * rden * rden);

            zs[j] = inside ? zin : xx;
            ls[j] = inside ? ldin : 0.0f;
        }

        int addr = base + (row0 + r * 16) * 512 + icol;
        vf4 zq = {zs[0], zs[1], zs[2], zs[3]};
        vf4 lq = {ls[0], ls[1], ls[2], ls[3]};
        __builtin_nontemporal_store(zq, reinterpret_cast<vf4*>(out + addr));
        __builtin_nontemporal_store(lq, reinterpret_cast<vf4*>(out + NELEM + addr));
    }
}

extern "C" void kernel_launch(void* const* d_in, const int* in_sizes, int n_in,
                              void* d_out, int out_size, void* d_ws, size_t ws_size,
                              hipStream_t stream)
{
    const float* x = (const float*)d_in[0];
    const float* W = (const float*)d_in[1];
    const float* H = (const float*)d_in[2];
    const float* D = (const float*)d_in[3];
    float* out = (float*)d_out;
    float* ws  = (float*)d_ws;

    rqs_precompute<<<GI / 256, 256, 0, stream>>>(W, H, D, ws);

    int nblocks = 8 * (BATCH / ROWS_PB);   // 4096
    rqs_main<<<nblocks, 256, 0, stream>>>(x, ws, out);
}